// Round 1
// baseline (287.963 us; speedup 1.0000x reference)
//
#include <hip/hip_runtime.h>
#include <stdint.h>

#define DIN 32
#define DOUT 32
#define DE 13
#define XWC 448  // 13*32 (xw, [d][o]) + 32 (xb)

__device__ __forceinline__ float bf2f(unsigned short u) {
    return __uint_as_float(((uint32_t)u) << 16);
}
__device__ __forceinline__ unsigned short f2bf(float f) {
    uint32_t b = __float_as_uint(f);
    b += 0x7FFFu + ((b >> 16) & 1u);
    return (unsigned short)(b >> 16);
}

// Kernel A: xw[n, j] (bf16), j<416: j=d*32+o -> sum_i x[n,i]*nn_w[(i*32+o)*13+d]
//                             j>=416: o=j-416 -> sum_i x[n,i]*nn_b[i*32+o]
__global__ __launch_bounds__(256) void kA(const float* __restrict__ x,
        const float* __restrict__ nn_w, const float* __restrict__ nn_b,
        unsigned short* __restrict__ xw, int N) {
    __shared__ float wcat[32 * XWC];  // [i][j], 57344 B
    const int tid = threadIdx.x;
    for (int t = tid; t < 32 * XWC; t += 256) {
        int i = t / XWC, j = t % XWC;
        float v;
        if (j < 416) { int d = j >> 5, o = j & 31; v = nn_w[(i * 32 + o) * 13 + d]; }
        else         { v = nn_b[i * 32 + (j - 416)]; }
        wcat[t] = v;
    }
    __syncthreads();
    const int lane = tid & 63;
    const int wave = (blockIdx.x * 256 + tid) >> 6;
    const int nwaves = (gridDim.x * 256) >> 6;
    const int ngroups = N >> 3;  // 8 nodes per wave-group (N=100000 divisible)
    for (int g = wave; g < ngroups; g += nwaves) {
        const int n0 = g << 3;
        float xv[8];
        #pragma unroll
        for (int m = 0; m < 8; ++m) xv[m] = x[(size_t)(n0 + m) * 32 + (lane & 31)];
        float acc[8][7];
        #pragma unroll
        for (int m = 0; m < 8; ++m)
            #pragma unroll
            for (int k = 0; k < 7; ++k) acc[m][k] = 0.f;
        #pragma unroll 4
        for (int i = 0; i < 32; ++i) {
            float wv[7];
            #pragma unroll
            for (int k = 0; k < 7; ++k) wv[k] = wcat[i * XWC + k * 64 + lane];
            #pragma unroll
            for (int m = 0; m < 8; ++m) {
                float xi = __shfl(xv[m], i, 32);
                #pragma unroll
                for (int k = 0; k < 7; ++k) acc[m][k] = fmaf(xi, wv[k], acc[m][k]);
            }
        }
        #pragma unroll
        for (int m = 0; m < 8; ++m) {
            unsigned short* dstp = xw + (size_t)(n0 + m) * XWC;
            #pragma unroll
            for (int k = 0; k < 7; ++k) dstp[k * 64 + lane] = f2bf(acc[m][k]);
        }
    }
}

// Kernel B: per-edge message + atomic scatter. Half-wave (32 lanes) per edge, lane = o.
__global__ __launch_bounds__(256) void kB(const unsigned short* __restrict__ xw,
        const float* __restrict__ ea, const int* __restrict__ ei,
        float* __restrict__ agg, float* __restrict__ cnt, int E) {
    const int o = threadIdx.x & 31;
    int hw = (blockIdx.x * 256 + threadIdx.x) >> 5;
    const int nhw = (gridDim.x * 256) >> 5;
    for (int e = hw; e < E; e += nhw) {
        const int s = ei[e];
        const int dst = ei[E + e];
        const unsigned short* base = xw + (size_t)s * XWC;
        const float* eap = ea + (size_t)e * 13;
        float acc = bf2f(base[416 + o]);
        #pragma unroll
        for (int dd = 0; dd < 13; ++dd)
            acc = fmaf(eap[dd], bf2f(base[dd * 32 + o]), acc);
        atomicAdd(&agg[(size_t)dst * 32 + o], acc);
        if (o == 0) atomicAdd(&cnt[dst], 1.0f);
    }
}

// Fallback (small ws): direct per-edge compute, nn_w in LDS.
__global__ __launch_bounds__(256) void kDirect(const float* __restrict__ x,
        const float* __restrict__ ea, const int* __restrict__ ei,
        const float* __restrict__ nn_w, const float* __restrict__ nn_b,
        float* __restrict__ agg, float* __restrict__ cnt, int E) {
    __shared__ float wT[13 * 1024];  // [d][io]
    __shared__ float nbl[1024];
    const int tid = threadIdx.x;
    for (int t = tid; t < 13 * 1024; t += 256) {
        int d = t >> 10, io = t & 1023;
        wT[t] = nn_w[io * 13 + d];
    }
    for (int t = tid; t < 1024; t += 256) nbl[t] = nn_b[t];
    __syncthreads();
    const int o = tid & 31;
    int hw = (blockIdx.x * 256 + tid) >> 5;
    const int nhw = (gridDim.x * 256) >> 5;
    for (int e = hw; e < E; e += nhw) {
        const int s = ei[e];
        const int dst = ei[E + e];
        float xv = x[(size_t)s * 32 + o];
        float eav[13];
        #pragma unroll
        for (int dd = 0; dd < 13; ++dd) eav[dd] = ea[(size_t)e * 13 + dd];
        float acc = 0.f;
        for (int i = 0; i < 32; ++i) {
            int io = i * 32 + o;
            float w = nbl[io];
            #pragma unroll
            for (int dd = 0; dd < 13; ++dd) w = fmaf(eav[dd], wT[dd * 1024 + io], w);
            acc = fmaf(__shfl(xv, i, 32), w, acc);
        }
        atomicAdd(&agg[(size_t)dst * 32 + o], acc);
        if (o == 0) atomicAdd(&cnt[dst], 1.0f);
    }
}

// Kernel C: mean + root matmul + bias + celu + GRU step + relu residual.
// Half-wave per node (lane = o), 4 nodes per iteration.
__global__ __launch_bounds__(256) void kC(const float* __restrict__ x,
        const float* __restrict__ agg, const float* __restrict__ cnt,
        const float* __restrict__ root, const float* __restrict__ bias,
        const float* __restrict__ w_ih, const float* __restrict__ w_hh,
        const float* __restrict__ b_ih, const float* __restrict__ b_hh,
        float* __restrict__ out, float* __restrict__ hnew, int N) {
    __shared__ float rootl[1024];           // [i][o]
    __shared__ float wihl[3072];            // [i][r] (transposed: lane reads i*96+r)
    __shared__ float whhl[3072];
    __shared__ float biasl[32], bihl[96], bhhl[96];
    const int tid = threadIdx.x;
    for (int t = tid; t < 1024; t += 256) rootl[t] = root[t];
    for (int t = tid; t < 3072; t += 256) {
        int r = t / 32, i = t % 32;
        wihl[i * 96 + r] = w_ih[t];
        whhl[i * 96 + r] = w_hh[t];
    }
    if (tid < 32) biasl[tid] = bias[tid];
    if (tid < 96) { bihl[tid] = b_ih[tid]; bhhl[tid] = b_hh[tid]; }
    __syncthreads();
    const int o = tid & 31;
    int hw = (blockIdx.x * 256 + tid) >> 5;
    const int nhw = (gridDim.x * 256) >> 5;
    const int ngroups = N >> 2;  // N=100000 divisible by 4
    for (int g = hw; g < ngroups; g += nhw) {
        const int n0 = g << 2;
        float xv[4], conv[4];
        #pragma unroll
        for (int m = 0; m < 4; ++m) {
            xv[m] = x[(size_t)(n0 + m) * 32 + o];
            float c = cnt[n0 + m];
            conv[m] = agg[(size_t)(n0 + m) * 32 + o] / fmaxf(c, 1.0f) + biasl[o];
        }
        for (int i = 0; i < 32; ++i) {
            float rv = rootl[i * 32 + o];
            #pragma unroll
            for (int m = 0; m < 4; ++m)
                conv[m] = fmaf(__shfl(xv[m], i, 32), rv, conv[m]);
        }
        float cv[4];
        #pragma unroll
        for (int m = 0; m < 4; ++m) {
            float v = conv[m];
            cv[m] = v > 0.f ? v : (expf(v) - 1.f);   // celu, alpha=1
        }
        float ri[4], zi[4], ni[4], rh[4], zh[4], nh[4];
        #pragma unroll
        for (int m = 0; m < 4; ++m) {
            ri[m] = bihl[o]; zi[m] = bihl[32 + o]; ni[m] = bihl[64 + o];
            rh[m] = bhhl[o]; zh[m] = bhhl[32 + o]; nh[m] = bhhl[64 + o];
        }
        for (int i = 0; i < 32; ++i) {
            float w0 = wihl[i * 96 + o], w1 = wihl[i * 96 + 32 + o], w2 = wihl[i * 96 + 64 + o];
            float u0 = whhl[i * 96 + o], u1 = whhl[i * 96 + 32 + o], u2 = whhl[i * 96 + 64 + o];
            #pragma unroll
            for (int m = 0; m < 4; ++m) {
                float ci = __shfl(cv[m], i, 32);
                float xi = __shfl(xv[m], i, 32);
                ri[m] = fmaf(ci, w0, ri[m]);
                zi[m] = fmaf(ci, w1, zi[m]);
                ni[m] = fmaf(ci, w2, ni[m]);
                rh[m] = fmaf(xi, u0, rh[m]);
                zh[m] = fmaf(xi, u1, zh[m]);
                nh[m] = fmaf(xi, u2, nh[m]);
            }
        }
        #pragma unroll
        for (int m = 0; m < 4; ++m) {
            float r = 1.f / (1.f + expf(-(ri[m] + rh[m])));
            float z = 1.f / (1.f + expf(-(zi[m] + zh[m])));
            float nn = tanhf(ni[m] + r * nh[m]);
            float h = (1.f - z) * nn + z * xv[m];    // h0 = x
            float ov = h + xv[m];                    // residual
            out[(size_t)(n0 + m) * 32 + o] = ov > 0.f ? ov : 0.f;
            hnew[(size_t)(n0 + m) * 32 + o] = h;
        }
    }
}

extern "C" void kernel_launch(void* const* d_in, const int* in_sizes, int n_in,
                              void* d_out, int out_size, void* d_ws, size_t ws_size,
                              hipStream_t stream) {
    const float* x    = (const float*)d_in[0];
    const float* ea   = (const float*)d_in[1];
    const float* nn_w = (const float*)d_in[2];
    const float* nn_b = (const float*)d_in[3];
    const float* root = (const float*)d_in[4];
    const float* bias = (const float*)d_in[5];
    const float* w_ih = (const float*)d_in[6];
    const float* w_hh = (const float*)d_in[7];
    const float* b_ih = (const float*)d_in[8];
    const float* b_hh = (const float*)d_in[9];
    const int*   ei   = (const int*)d_in[10];
    const int N = in_sizes[0] / DIN;
    const int E = in_sizes[10] / 2;
    float* out  = (float*)d_out;
    float* hnew = out + (size_t)N * DOUT;

    const size_t xw_bytes  = (size_t)N * XWC * sizeof(unsigned short);  // ~89.6 MB
    const size_t agg_bytes = (size_t)N * 32 * sizeof(float);            // 12.8 MB
    const size_t cnt_bytes = (size_t)N * sizeof(float);                 // 0.4 MB

    if (ws_size >= xw_bytes + agg_bytes + cnt_bytes) {
        unsigned short* xw = (unsigned short*)d_ws;
        float* agg = (float*)((char*)d_ws + xw_bytes);
        float* cnt = (float*)((char*)d_ws + xw_bytes + agg_bytes);
        hipMemsetAsync(agg, 0, agg_bytes + cnt_bytes, stream);
        kA<<<512, 256, 0, stream>>>(x, nn_w, nn_b, xw, N);
        kB<<<2048, 256, 0, stream>>>(xw, ea, ei, agg, cnt, E);
        kC<<<1024, 256, 0, stream>>>(x, agg, cnt, root, bias, w_ih, w_hh,
                                     b_ih, b_hh, out, hnew, N);
    } else {
        // Fallback: direct per-edge compute; needs only 13.2 MB of ws.
        float* agg = (float*)d_ws;
        float* cnt = (float*)((char*)d_ws + agg_bytes);
        hipMemsetAsync(agg, 0, agg_bytes + cnt_bytes, stream);
        kDirect<<<2048, 256, 0, stream>>>(x, ea, ei, nn_w, nn_b, agg, cnt, E);
        kC<<<1024, 256, 0, stream>>>(x, agg, cnt, root, bias, w_ih, w_hh,
                                     b_ih, b_hh, out, hnew, N);
    }
}

// Round 2
// 187.995 us; speedup vs baseline: 1.5318x; 1.5318x over previous
//
#include <hip/hip_runtime.h>
#include <stdint.h>

#define DIN 32
#define DOUT 32
#define DE 13
#define XWC 448  // 32 outputs * 14 (13 edge-dims + 1 bias term), col = o*14 + dp

typedef float f32x4 __attribute__((ext_vector_type(4)));
typedef short s16x8 __attribute__((ext_vector_type(8)));

__device__ __forceinline__ float bf2f_lo(uint32_t u) { return __uint_as_float(u << 16); }
__device__ __forceinline__ float bf2f_hi(uint32_t u) { return __uint_as_float(u & 0xffff0000u); }
__device__ __forceinline__ unsigned short f2bf(float f) {
    uint32_t b = __float_as_uint(f);
    b += 0x7FFFu + ((b >> 16) & 1u);
    return (unsigned short)(b >> 16);
}
__device__ __forceinline__ float sigm(float v) { return 1.f / (1.f + __expf(-v)); }
__device__ __forceinline__ float tanh_fast(float v) { return 2.f / (1.f + __expf(-2.f * v)) - 1.f; }

// ---------------------------------------------------------------------------
// kA: xw[n][o*14+dp] = bf16( sum_i x[n,i] * W[i][col] )
//   W[i][o*14+dp] = dp<13 ? nn_w[(i*32+o)*13+dp] : nn_b[i*32+o]
// MFMA 16x16x32 bf16, one wave per 16-node strip, 28 column tiles from LDS.
// ---------------------------------------------------------------------------
__global__ __launch_bounds__(256) void kA(const float* __restrict__ x,
        const float* __restrict__ nn_w, const float* __restrict__ nn_b,
        unsigned short* __restrict__ xw, int N) {
    __shared__ unsigned short Bl[28 * 64 * 8];  // [tile][lane][j] pre-swizzled B-frags
    const int tid = threadIdx.x;
    for (int t = tid; t < 28 * 64 * 8; t += 256) {
        int j = t & 7;
        int lane = (t >> 3) & 63;
        int jt = t >> 9;
        int i = ((lane >> 4) << 3) + j;        // k-index (input dim)
        int col = jt * 16 + (lane & 15);
        int o = col / 14, dp = col % 14;
        float v = (dp < 13) ? nn_w[(i * 32 + o) * 13 + dp] : nn_b[i * 32 + o];
        Bl[t] = f2bf(v);
    }
    __syncthreads();
    const int lane = tid & 63;
    const int wave = (blockIdx.x * 256 + tid) >> 6;
    const int nw = (gridDim.x * 256) >> 6;
    const int nstrips = N >> 4;  // N % 16 == 0
    const int rowb = (lane >> 4) << 2;
    const int c15 = lane & 15;
    for (int s = wave; s < nstrips; s += nw) {
        const int n0 = s << 4;
        const float* xp = x + (size_t)(n0 + c15) * 32 + ((lane >> 4) << 3);
        f32x4 x0 = *(const f32x4*)xp;
        f32x4 x1 = *(const f32x4*)(xp + 4);
        s16x8 a;
        a[0] = (short)f2bf(x0[0]); a[1] = (short)f2bf(x0[1]);
        a[2] = (short)f2bf(x0[2]); a[3] = (short)f2bf(x0[3]);
        a[4] = (short)f2bf(x1[0]); a[5] = (short)f2bf(x1[1]);
        a[6] = (short)f2bf(x1[2]); a[7] = (short)f2bf(x1[3]);
        unsigned short* outp = xw + (size_t)n0 * XWC;
        #pragma unroll 4
        for (int jt = 0; jt < 28; ++jt) {
            s16x8 b = *(const s16x8*)&Bl[(jt * 64 + lane) * 8];
            f32x4 acc = {0.f, 0.f, 0.f, 0.f};
            acc = __builtin_amdgcn_mfma_f32_16x16x32_bf16(a, b, acc, 0, 0, 0);
            #pragma unroll
            for (int r = 0; r < 4; ++r)
                outp[(size_t)(rowb + r) * XWC + jt * 16 + c15] = f2bf(acc[r]);
        }
    }
}

// ---------------------------------------------------------------------------
// kB: per-edge message + atomic scatter. Half-wave per edge, lane = o.
// Each lane's 14 table values are contiguous (28 B) -> 7 dword loads.
// ---------------------------------------------------------------------------
__global__ __launch_bounds__(256) void kB(const unsigned short* __restrict__ xw,
        const float* __restrict__ ea, const int* __restrict__ ei,
        float* __restrict__ agg, float* __restrict__ cnt, int E) {
    const int o = threadIdx.x & 31;
    int hw = (blockIdx.x * 256 + threadIdx.x) >> 5;
    const int nhw = (gridDim.x * 256) >> 5;
    for (int e = hw; e < E; e += nhw) {
        const int s = ei[e];
        const int dst = ei[E + e];
        const uint32_t* p = (const uint32_t*)(xw + (size_t)s * XWC + o * 14);
        uint32_t u[7];
        #pragma unroll
        for (int k = 0; k < 7; ++k) u[k] = p[k];
        const float* eap = ea + (size_t)e * 13;
        float acc = bf2f_hi(u[6]);  // dp=13: bias term
        #pragma unroll
        for (int k = 0; k < 6; ++k) {
            acc = fmaf(eap[2 * k],     bf2f_lo(u[k]), acc);
            acc = fmaf(eap[2 * k + 1], bf2f_hi(u[k]), acc);
        }
        acc = fmaf(eap[12], bf2f_lo(u[6]), acc);
        atomicAdd(&agg[(size_t)dst * 32 + o], acc);
        if (o == 0) atomicAdd(&cnt[dst], 1.0f);
    }
}

// Fallback (small ws): direct per-edge compute, nn_w in LDS.
__global__ __launch_bounds__(256) void kDirect(const float* __restrict__ x,
        const float* __restrict__ ea, const int* __restrict__ ei,
        const float* __restrict__ nn_w, const float* __restrict__ nn_b,
        float* __restrict__ agg, float* __restrict__ cnt, int E) {
    __shared__ float wT[13 * 1024];
    __shared__ float nbl[1024];
    const int tid = threadIdx.x;
    for (int t = tid; t < 13 * 1024; t += 256) {
        int d = t >> 10, io = t & 1023;
        wT[t] = nn_w[io * 13 + d];
    }
    for (int t = tid; t < 1024; t += 256) nbl[t] = nn_b[t];
    __syncthreads();
    const int o = tid & 31;
    int hw = (blockIdx.x * 256 + tid) >> 5;
    const int nhw = (gridDim.x * 256) >> 5;
    for (int e = hw; e < E; e += nhw) {
        const int s = ei[e];
        const int dst = ei[E + e];
        float xv = x[(size_t)s * 32 + o];
        float eav[13];
        #pragma unroll
        for (int dd = 0; dd < 13; ++dd) eav[dd] = ea[(size_t)e * 13 + dd];
        float acc = 0.f;
        for (int i = 0; i < 32; ++i) {
            int io = i * 32 + o;
            float w = nbl[io];
            #pragma unroll
            for (int dd = 0; dd < 13; ++dd) w = fmaf(eav[dd], wT[dd * 1024 + io], w);
            acc = fmaf(__shfl(xv, i, 32), w, acc);
        }
        atomicAdd(&agg[(size_t)dst * 32 + o], acc);
        if (o == 0) atomicAdd(&cnt[dst], 1.0f);
    }
}

// ---------------------------------------------------------------------------
// kC: mean + root + celu + GRU + relu, MFMA version. One wave per 16 nodes.
// MFMA1: x @ [root(32) | w_hh^T(96)] -> 8 tiles (bias pre-init'd in acc).
// celu -> LDS roundtrip (C-layout -> A-layout), MFMA2: c @ w_ih^T -> 6 tiles.
// ---------------------------------------------------------------------------
__global__ __launch_bounds__(256) void kC(const float* __restrict__ x,
        const float* __restrict__ agg, const float* __restrict__ cnt,
        const float* __restrict__ root, const float* __restrict__ bias,
        const float* __restrict__ w_ih, const float* __restrict__ w_hh,
        const float* __restrict__ b_ih, const float* __restrict__ b_hh,
        float* __restrict__ out, float* __restrict__ hnew, int N) {
    __shared__ unsigned short Bl[14 * 64 * 8];   // 8 tiles W1, 6 tiles W2
    __shared__ unsigned short clds[4][16 * 32];  // per-wave c roundtrip
    const int tid = threadIdx.x;
    for (int t = tid; t < 14 * 64 * 8; t += 256) {
        int j = t & 7;
        int lane = (t >> 3) & 63;
        int tt = t >> 9;
        int i = ((lane >> 4) << 3) + j;
        int c = lane & 15;
        float v;
        if (tt < 8) {
            int col = tt * 16 + c;
            v = (col < 32) ? root[i * 32 + col] : w_hh[(col - 32) * 32 + i];
        } else {
            v = w_ih[((tt - 8) * 16 + c) * 32 + i];
        }
        Bl[t] = f2bf(v);
    }
    __syncthreads();
    const int lane = tid & 63;
    const int wv = tid >> 6;
    const int c15 = lane & 15;
    const int rowb = (lane >> 4) << 2;
    float binit[14];
    #pragma unroll
    for (int t = 0; t < 2; ++t) binit[t] = bias[t * 16 + c15];
    #pragma unroll
    for (int t = 2; t < 8; ++t) binit[t] = b_hh[t * 16 + c15 - 32];
    #pragma unroll
    for (int u = 0; u < 6; ++u) binit[8 + u] = b_ih[u * 16 + c15];
    int wave = (blockIdx.x * 256 + tid) >> 6;
    const int nw = (gridDim.x * 256) >> 6;
    const int nstrips = N >> 4;
    for (int s = wave; s < nstrips; s += nw) {
        const int n0 = s << 4;
        const float* xp = x + (size_t)(n0 + c15) * 32 + ((lane >> 4) << 3);
        f32x4 x0 = *(const f32x4*)xp;
        f32x4 x1 = *(const f32x4*)(xp + 4);
        s16x8 a;
        a[0] = (short)f2bf(x0[0]); a[1] = (short)f2bf(x0[1]);
        a[2] = (short)f2bf(x0[2]); a[3] = (short)f2bf(x0[3]);
        a[4] = (short)f2bf(x1[0]); a[5] = (short)f2bf(x1[1]);
        a[6] = (short)f2bf(x1[2]); a[7] = (short)f2bf(x1[3]);
        f32x4 D[8];
        #pragma unroll
        for (int t = 0; t < 8; ++t) {
            s16x8 b = *(const s16x8*)&Bl[(t * 64 + lane) * 8];
            f32x4 ci = {binit[t], binit[t], binit[t], binit[t]};
            D[t] = __builtin_amdgcn_mfma_f32_16x16x32_bf16(a, b, ci, 0, 0, 0);
        }
        float xr[4][2];
        #pragma unroll
        for (int r = 0; r < 4; ++r) {
            const int n = n0 + rowb + r;
            float cn = fmaxf(cnt[n], 1.f);
            #pragma unroll
            for (int t = 0; t < 2; ++t) {
                float ag = agg[(size_t)n * 32 + t * 16 + c15];
                xr[r][t] = x[(size_t)n * 32 + t * 16 + c15];
                float conv = ag / cn + D[t][r];
                float cv = conv > 0.f ? conv : (__expf(conv) - 1.f);  // celu
                clds[wv][(rowb + r) * 32 + t * 16 + c15] = f2bf(cv);
            }
        }
        // A2-frag from LDS (wave-private producer/consumer; compiler inserts lgkmcnt)
        s16x8 a2 = *(const s16x8*)&clds[wv][c15 * 32 + ((lane >> 4) << 3)];
        f32x4 G[6];
        #pragma unroll
        for (int u = 0; u < 6; ++u) {
            s16x8 b = *(const s16x8*)&Bl[((8 + u) * 64 + lane) * 8];
            f32x4 ci = {binit[8 + u], binit[8 + u], binit[8 + u], binit[8 + u]};
            G[u] = __builtin_amdgcn_mfma_f32_16x16x32_bf16(a2, b, ci, 0, 0, 0);
        }
        #pragma unroll
        for (int t = 0; t < 2; ++t) {
            #pragma unroll
            for (int r = 0; r < 4; ++r) {
                float rg = sigm(G[t][r] + D[2 + t][r]);
                float z  = sigm(G[2 + t][r] + D[4 + t][r]);
                float nn = tanh_fast(G[4 + t][r] + rg * D[6 + t][r]);
                float h  = (1.f - z) * nn + z * xr[r][t];
                float ov = h + xr[r][t];
                size_t oi = (size_t)(n0 + rowb + r) * 32 + t * 16 + c15;
                out[oi]  = ov > 0.f ? ov : 0.f;
                hnew[oi] = h;
            }
        }
    }
}

extern "C" void kernel_launch(void* const* d_in, const int* in_sizes, int n_in,
                              void* d_out, int out_size, void* d_ws, size_t ws_size,
                              hipStream_t stream) {
    const float* x    = (const float*)d_in[0];
    const float* ea   = (const float*)d_in[1];
    const float* nn_w = (const float*)d_in[2];
    const float* nn_b = (const float*)d_in[3];
    const float* root = (const float*)d_in[4];
    const float* bias = (const float*)d_in[5];
    const float* w_ih = (const float*)d_in[6];
    const float* w_hh = (const float*)d_in[7];
    const float* b_ih = (const float*)d_in[8];
    const float* b_hh = (const float*)d_in[9];
    const int*   ei   = (const int*)d_in[10];
    const int N = in_sizes[0] / DIN;
    const int E = in_sizes[10] / 2;
    float* out  = (float*)d_out;
    float* hnew = out + (size_t)N * DOUT;

    const size_t xw_bytes  = (size_t)N * XWC * sizeof(unsigned short);
    const size_t agg_bytes = (size_t)N * 32 * sizeof(float);
    const size_t cnt_bytes = (size_t)N * sizeof(float);

    if (ws_size >= xw_bytes + agg_bytes + cnt_bytes) {
        unsigned short* xw = (unsigned short*)d_ws;
        float* agg = (float*)((char*)d_ws + xw_bytes);
        float* cnt = (float*)((char*)d_ws + xw_bytes + agg_bytes);
        hipMemsetAsync(agg, 0, agg_bytes + cnt_bytes, stream);
        kA<<<512, 256, 0, stream>>>(x, nn_w, nn_b, xw, N);
        kB<<<2048, 256, 0, stream>>>(xw, ea, ei, agg, cnt, E);
        kC<<<512, 256, 0, stream>>>(x, agg, cnt, root, bias, w_ih, w_hh,
                                    b_ih, b_hh, out, hnew, N);
    } else {
        float* agg = (float*)d_ws;
        float* cnt = (float*)((char*)d_ws + agg_bytes);
        hipMemsetAsync(agg, 0, agg_bytes + cnt_bytes, stream);
        kDirect<<<2048, 256, 0, stream>>>(x, ea, ei, nn_w, nn_b, agg, cnt, E);
        kC<<<512, 256, 0, stream>>>(x, agg, cnt, root, bias, w_ih, w_hh,
                                    b_ih, b_hh, out, hnew, N);
    }
}